// Round 1
// baseline (133.447 us; speedup 1.0000x reference)
//
#include <hip/hip_runtime.h>
#include <math.h>

// Problem constants (RESUS_NN_2327872274812): Q=8192, S=30, D=512.
#define QN 8192
#define SN 30
#define DN 512
#define QT 32            // queries per block
#define BLK 512          // threads per block: 32 q-slots x 16 d-chunk groups
#define CHUNK 32         // d per thread (512 / 16)

__global__ __launch_bounds__(BLK, 1)
void resus_fused(const float* __restrict__ query,      // [Q][D]
                 const float* __restrict__ support,    // [S][D]
                 const float* __restrict__ support_y,  // [S]
                 const float* __restrict__ support_pr, // [S]
                 const float* __restrict__ query_pr,   // [Q]
                 const float* __restrict__ fc1_w,      // [D]
                 const float* __restrict__ adj_scale,  // [30]
                 const float* __restrict__ adj_bias,   // [30]
                 const int*   __restrict__ num_samples,// [1]
                 float* __restrict__ out)              // [2*Q]
{
    // sv: support staged in LDS, row-major [30][512], 61440 B.
    // After the main loop it is re-used (aliased) as the per-query partial
    // accumulator part[32][65] (stride 65 -> conflict-free ds_add banks).
    __shared__ float sv[SN * DN];
    __shared__ float w_lds[DN];
    __shared__ float dy[SN];

    const int tid = threadIdx.x;

    // ---- stage support + w + delta_y ----
    for (int i = tid; i < SN * DN; i += BLK) sv[i] = support[i];
    if (tid < DN) w_lds[tid] = fc1_w[tid];
    if (tid < SN) {
        // delta_y = support_y - sigmoid(support_predict)
        dy[tid] = support_y[tid] - 1.0f / (1.0f + expf(-support_pr[tid]));
    }
    __syncthreads();

    const int ql = tid & (QT - 1);     // 0..31  query slot
    const int c  = tid >> 5;           // 0..15  d-chunk group (2 per wave)
    const int q  = blockIdx.x * QT + ql;

    const float* qrow = query + q * DN + c * CHUNK;
    const float* wrow = w_lds + c * CHUNK;
    const float* srow = sv + c * CHUNK;

    float score[SN];
    float sq[SN];
#pragma unroll
    for (int s = 0; s < SN; ++s) { score[s] = 0.0f; sq[s] = 0.0f; }

    // ---- main sweep: this thread's 32 d-values, all 30 support rows ----
#pragma unroll
    for (int g = 0; g < CHUNK / 4; ++g) {           // 8 groups of 4 d
        const float4 qv = *reinterpret_cast<const float4*>(qrow + 4 * g);
        const float4 wv = *reinterpret_cast<const float4*>(wrow + 4 * g);
        const float* sp = srow + 4 * g;
#pragma unroll
        for (int s = 0; s < SN; ++s) {
            const float4 s4 = *reinterpret_cast<const float4*>(sp + s * DN);
            float d0 = qv.x - s4.x;
            float d1 = qv.y - s4.y;
            float d2 = qv.z - s4.z;
            float d3 = qv.w - s4.w;
            score[s] = fmaf(wv.x, fabsf(d0), score[s]);
            score[s] = fmaf(wv.y, fabsf(d1), score[s]);
            score[s] = fmaf(wv.z, fabsf(d2), score[s]);
            score[s] = fmaf(wv.w, fabsf(d3), score[s]);
            sq[s] = fmaf(d0, d0, sq[s]);
            sq[s] = fmaf(d1, d1, sq[s]);
            sq[s] = fmaf(d2, d2, sq[s]);
            sq[s] = fmaf(d3, d3, sq[s]);
        }
    }

    // ---- combine the 16 d-chunk partials per query via LDS atomics ----
    __syncthreads();                 // everyone done reading sv
    float* part = sv;                // alias: part[32][65] = 8320 B
    for (int i = tid; i < QT * 65; i += BLK) part[i] = 0.0f;
    __syncthreads();

    float* prow = part + ql * 65;
#pragma unroll
    for (int s = 0; s < SN; ++s) {
        atomicAdd(&prow[s], score[s]);
        atomicAdd(&prow[SN + s], sq[s]);
    }
    __syncthreads();

    // ---- epilogue: softmax over s, weighted residual, mean L2 ----
    if (tid < QT) {
        const int qg = blockIdx.x * QT + tid;
        const float* r = part + tid * 65;

        float m = -1e30f;
#pragma unroll
        for (int s = 0; s < SN; ++s) m = fmaxf(m, r[s]);

        float den = 0.0f, num = 0.0f, l2 = 0.0f;
#pragma unroll
        for (int s = 0; s < SN; ++s) {
            float e = expf(r[s] - m);   // fc1_b cancels in softmax
            den += e;
            num = fmaf(dy[s], e, num);
            l2 += sqrtf(r[SN + s]);
        }

        const int ns = num_samples[0];
        const float sc = fabsf(adj_scale[ns - 1]);
        const float bi = adj_bias[ns - 1];

        out[qg]      = num / den * sc + bi + query_pr[qg];
        out[QN + qg] = l2 * (1.0f / (float)SN);
    }
}

extern "C" void kernel_launch(void* const* d_in, const int* in_sizes, int n_in,
                              void* d_out, int out_size, void* d_ws, size_t ws_size,
                              hipStream_t stream)
{
    const float* query      = (const float*)d_in[0];
    const float* support    = (const float*)d_in[1];
    const float* support_y  = (const float*)d_in[2];
    const float* support_pr = (const float*)d_in[3];
    const float* query_pr   = (const float*)d_in[4];
    const float* fc1_w      = (const float*)d_in[5];
    // d_in[6] = fc1_b: cancels in softmax, unused
    const float* adj_scale  = (const float*)d_in[7];
    const float* adj_bias   = (const float*)d_in[8];
    const int*   num_s      = (const int*)d_in[9];
    float* out = (float*)d_out;

    dim3 grid(QN / QT);   // 256 blocks -> 1 per CU
    dim3 block(BLK);      // 512 threads = 8 waves
    hipLaunchKernelGGL(resus_fused, grid, block, 0, stream,
                       query, support, support_y, support_pr, query_pr,
                       fc1_w, adj_scale, adj_bias, num_s, out);
}